// Round 8
// baseline (788.678 us; speedup 1.0000x reference)
//
#include <hip/hip_runtime.h>

#define NROWS 65536
#define KCODE 2048
#define DDIM  128

static constexpr float DECAYF = 0.99f;
static constexpr float OMDF   = (float)(1.0 - 0.99);
static constexpr float EPSF   = 1e-5f;
static constexpr float KEPSF  = (float)(2048.0 * 1e-5);
static constexpr float MARGIN = 1e-3f;

typedef __attribute__((ext_vector_type(8))) short bf16x8;
typedef __attribute__((ext_vector_type(4))) float f32x4;

__device__ __forceinline__ unsigned int bf16_rne_bits(float f) {
  unsigned int u = __builtin_bit_cast(unsigned int, f);
  return (u + 0x7fffu + ((u >> 16) & 1u)) >> 16;
}

// ---------------- kernel: split codebook into bf16 hi/lo planes ----------------
__global__ __launch_bounds__(256) void k_split(const float* __restrict__ emb,
                                               unsigned short* __restrict__ ehi,
                                               unsigned short* __restrict__ elo) {
  int i = blockIdx.x * 256 + threadIdx.x;
  float f = emb[i];
  unsigned int hr = bf16_rne_bits(f);
  float hif = __builtin_bit_cast(float, hr << 16);
  float lo = f - hif;                    // exact (Sterbenz)
  unsigned int lr = bf16_rne_bits(lo);
  ehi[i] = (unsigned short)hr;
  elo[i] = (unsigned short)lr;
}

// ---------------- kernel: per-code sum of squares (exact ref order) ----------------
__global__ __launch_bounds__(256) void k_sumsq_emb(const float* __restrict__ emb,
                                                   float* __restrict__ se) {
#pragma clang fp contract(off)
  int k = blockIdx.x * 256 + threadIdx.x;
  if (k >= KCODE) return;
  const float* row = emb + (size_t)k * DDIM;
  float s = 0.f;
#pragma unroll
  for (int d = 0; d < DDIM; ++d) {
    float q = row[d] * row[d];
    s = s + q;
  }
  se[k] = s;
}

// ---------------- kernel: MFMA screen, LDS-staged codebook ----------------
// Per block: 128 rows (4 waves x 32). Codebook tile (16 codes, hi+lo = 8KB)
// double-buffered in LDS with XOR swizzle (byte ^= ((row&7)<<4)) on both the
// ds_write and ds_read side. 3 independent 4-deep MFMA accumulator chains
// (hh, hl, lh) per 16-row tile; d~ = se - 2*(hh+hl+lh), err <~ 1e-4 << MARGIN.
__global__ __launch_bounds__(256, 2) void k_screen(
    const float* __restrict__ x, const unsigned short* __restrict__ ehi,
    const unsigned short* __restrict__ elo, const float* __restrict__ se,
    float* __restrict__ out_idxf, int* __restrict__ idx,
    int* __restrict__ flaglist, int* __restrict__ flagcnt) {
  const int tid = threadIdx.x;
  const int lane = tid & 63;
  const int wid = tid >> 6;
  const int rowbase = (blockIdx.x * 4 + wid) * 32;
  const int l15 = lane & 15, l4 = lane >> 4;

  __shared__ __align__(16) char lds[2][8192];
  char* lbase = &lds[0][0];

  // ---- A fragments: 2 row-tiles x 4 k-frags, hi+lo split on the fly ----
  bf16x8 ahi0[4], alo0[4], ahi1[4], alo1[4];
#pragma unroll
  for (int t = 0; t < 2; ++t) {
#pragma unroll
    for (int f = 0; f < 4; ++f) {
      const float4* s4 =
          (const float4*)(x + (size_t)(rowbase + t * 16 + l15) * DDIM + f * 32 + l4 * 8);
      float4 v0 = s4[0], v1 = s4[1];
      float fv[8] = {v0.x, v0.y, v0.z, v0.w, v1.x, v1.y, v1.z, v1.w};
      union { unsigned short u[8]; bf16x8 v; } H, L;
#pragma unroll
      for (int j = 0; j < 8; ++j) {
        unsigned int hr = bf16_rne_bits(fv[j]);
        float hif = __builtin_bit_cast(float, hr << 16);
        unsigned int lr = bf16_rne_bits(fv[j] - hif);
        H.u[j] = (unsigned short)hr;
        L.u[j] = (unsigned short)lr;
      }
      if (t == 0) { ahi0[f] = H.v; alo0[f] = L.v; }
      else        { ahi1[f] = H.v; alo1[f] = L.v; }
    }
  }

  // ---- swizzled LDS read addresses (loop-invariant) ----
  int raddr[2][4];
#pragma unroll
  for (int p = 0; p < 2; ++p)
#pragma unroll
    for (int f = 0; f < 4; ++f)
      raddr[p][f] = p * 4096 + ((l15 * 256 + f * 64 + l4 * 16) ^ ((l15 & 7) << 4));

  // ---- staging addresses: 256 threads x 32B cover the 8KB tile ----
  const unsigned short* splane = (tid & 128) ? elo : ehi;
  const int po0 = (tid & 127) * 32;                 // byte offset within 4KB plane
  const char* sp = (const char*)splane + po0;
  const int wplane = (tid >> 7) * 4096;
  const int waddr0 = wplane + (po0 ^ (((po0 >> 8) & 7) << 4));
  const int waddr1 = wplane + ((po0 + 16) ^ ((((po0 + 16) >> 8) & 7) << 4));

  float m1[8], m2[8];
  int k1[8];
#pragma unroll
  for (int s = 0; s < 8; ++s) { m1[s] = INFINITY; m2[s] = INFINITY; k1[s] = 0; }

  // prologue: stage group 0 into buffer 0
  {
    int4 v0 = *(const int4*)(sp);
    int4 v1 = *(const int4*)(sp + 16);
    *(int4*)(lbase + waddr0) = v0;
    *(int4*)(lbase + waddr1) = v1;
  }
  __syncthreads();

  int bufoff = 0;
#pragma unroll 2
  for (int g = 0; g < 128; ++g) {
    float sec = se[g * 16 + l15];                   // issued early, used in epilogue
    int4 nv0, nv1;
    if (g < 127) {                                  // T14: issue loads before compute
      nv0 = *(const int4*)(sp + (size_t)(g + 1) * 4096);
      nv1 = *(const int4*)(sp + (size_t)(g + 1) * 4096 + 16);
    }
    f32x4 hh0 = {0.f, 0.f, 0.f, 0.f}, hl0 = {0.f, 0.f, 0.f, 0.f}, lh0 = {0.f, 0.f, 0.f, 0.f};
    f32x4 hh1 = {0.f, 0.f, 0.f, 0.f}, hl1 = {0.f, 0.f, 0.f, 0.f}, lh1 = {0.f, 0.f, 0.f, 0.f};
#pragma unroll
    for (int f = 0; f < 4; ++f) {
      bf16x8 BH = *(const bf16x8*)(lbase + bufoff + raddr[0][f]);
      bf16x8 BL = *(const bf16x8*)(lbase + bufoff + raddr[1][f]);
      hh0 = __builtin_amdgcn_mfma_f32_16x16x32_bf16(ahi0[f], BH, hh0, 0, 0, 0);
      lh0 = __builtin_amdgcn_mfma_f32_16x16x32_bf16(alo0[f], BH, lh0, 0, 0, 0);
      hl0 = __builtin_amdgcn_mfma_f32_16x16x32_bf16(ahi0[f], BL, hl0, 0, 0, 0);
      hh1 = __builtin_amdgcn_mfma_f32_16x16x32_bf16(ahi1[f], BH, hh1, 0, 0, 0);
      lh1 = __builtin_amdgcn_mfma_f32_16x16x32_bf16(alo1[f], BH, lh1, 0, 0, 0);
      hl1 = __builtin_amdgcn_mfma_f32_16x16x32_bf16(ahi1[f], BL, hl1, 0, 0, 0);
    }
    int c_ = g * 16 + l15;
#pragma unroll
    for (int s = 0; s < 4; ++s) {
      float vv = fmaf(-2.f, (hh0[s] + hl0[s]) + lh0[s], sec);
      m2[s] = fminf(m2[s], fmaxf(vv, m1[s]));
      k1[s] = (vv < m1[s]) ? c_ : k1[s];
      m1[s] = fminf(m1[s], vv);
      float vw = fmaf(-2.f, (hh1[s] + hl1[s]) + lh1[s], sec);
      m2[s + 4] = fminf(m2[s + 4], fmaxf(vw, m1[s + 4]));
      k1[s + 4] = (vw < m1[s + 4]) ? c_ : k1[s + 4];
      m1[s + 4] = fminf(m1[s + 4], vw);
    }
    if (g < 127) {                                  // write into the OTHER buffer
      *(int4*)(lbase + (bufoff ^ 8192) + waddr0) = nv0;
      *(int4*)(lbase + (bufoff ^ 8192) + waddr1) = nv1;
    }
    __syncthreads();
    bufoff ^= 8192;
  }

  // cross-lane combine over the 16 cols (low 4 lane bits)
#pragma unroll
  for (int off = 1; off < 16; off <<= 1) {
#pragma unroll
    for (int s = 0; s < 8; ++s) {
      float om1 = __shfl_xor(m1[s], off);
      float om2 = __shfl_xor(m2[s], off);
      int ok1 = __shfl_xor(k1[s], off);
      m2[s] = fminf(fminf(m2[s], om2), fmaxf(m1[s], om1));
      k1[s] = (om1 < m1[s]) ? ok1 : k1[s];
      m1[s] = fminf(m1[s], om1);
    }
  }
  if (l15 == 0) {
#pragma unroll
    for (int s = 0; s < 8; ++s) {
      int row = rowbase + (s >> 2) * 16 + l4 * 4 + (s & 3);
      idx[row] = k1[s];
      out_idxf[row] = (float)k1[s];
      if (m2[s] - m1[s] <= MARGIN) {
        int p = atomicAdd(flagcnt, 1);
        if (p < NROWS) flaglist[p] = row;
      }
    }
  }
}

// ---------------- kernel: exact re-rank of flagged rows (ref-identical arithmetic) ----------------
__global__ __launch_bounds__(64) void k_exact(
    const float* __restrict__ x, const float* __restrict__ emb,
    const float* __restrict__ se, const int* __restrict__ flaglist,
    const int* __restrict__ flagcnt, int* __restrict__ idx,
    float* __restrict__ out_idxf) {
#pragma clang fp contract(off)
  int cnt = *flagcnt;
  if (cnt > NROWS) cnt = NROWS;
  int lane = threadIdx.x;
  for (int i = blockIdx.x; i < cnt; i += gridDim.x) {
    int row = flaglist[i];
    const float4* xp = (const float4*)(x + (size_t)row * DDIM);
    float4 xr[32];
#pragma unroll
    for (int j = 0; j < 32; ++j) xr[j] = xp[j];
    float sx = 0.f;
#pragma unroll
    for (int j = 0; j < 32; ++j) {
      float q0 = xr[j].x * xr[j].x; sx = sx + q0;
      float q1 = xr[j].y * xr[j].y; sx = sx + q1;
      float q2 = xr[j].z * xr[j].z; sx = sx + q2;
      float q3 = xr[j].w * xr[j].w; sx = sx + q3;
    }
    float bestd = INFINITY;
    int bestk = lane * 32;
    for (int cb = 0; cb < 32; cb += 4) {
      float c4[4] = {0.f, 0.f, 0.f, 0.f};
#pragma unroll
      for (int d4 = 0; d4 < 32; ++d4) {
#pragma unroll
        for (int u = 0; u < 4; ++u) {
          float4 e = ((const float4*)(emb + (size_t)(lane * 32 + cb + u) * DDIM))[d4];
          c4[u] = fmaf(e.x, xr[d4].x, c4[u]);
          c4[u] = fmaf(e.y, xr[d4].y, c4[u]);
          c4[u] = fmaf(e.z, xr[d4].z, c4[u]);
          c4[u] = fmaf(e.w, xr[d4].w, c4[u]);
        }
      }
#pragma unroll
      for (int u = 0; u < 4; ++u) {
        int c = lane * 32 + cb + u;
        float t = sx + se[c];
        float tw = 2.0f * c4[u];
        float d = t - tw;
        if (d < bestd) { bestd = d; bestk = c; }
      }
    }
#pragma unroll
    for (int off = 1; off < 64; off <<= 1) {
      float od = __shfl_xor(bestd, off);
      int ok = __shfl_xor(bestk, off);
      if (od < bestd || (od == bestd && ok < bestk)) { bestd = od; bestk = ok; }
    }
    if (lane == 0) { idx[row] = bestk; out_idxf[row] = (float)bestk; }
  }
}

// ------- kernel: gather/quantize + ST output + loss + EMA scatter -------
__global__ __launch_bounds__(256) void k_quant(const float* __restrict__ x,
                                               const float* __restrict__ emb,
                                               const int* __restrict__ idx,
                                               float* __restrict__ out_q,
                                               float* __restrict__ dw,
                                               float* __restrict__ dwe,
                                               double* __restrict__ loss_acc) {
#pragma clang fp contract(off)
  int t = blockIdx.x * 256 + threadIdx.x;
  int n = t >> 5, j = t & 31;
  int k = idx[n];
  float4 xv = ((const float4*)(x + (size_t)n * DDIM))[j];
  float4 ev = ((const float4*)(emb + (size_t)k * DDIM))[j];
  float d0 = ev.x - xv.x, d1 = ev.y - xv.y, d2 = ev.z - xv.z, d3 = ev.w - xv.w;
  float4 q;
  q.x = xv.x + d0; q.y = xv.y + d1; q.z = xv.z + d2; q.w = xv.w + d3;
  ((float4*)(out_q + (size_t)n * DDIM))[j] = q;

  // per-wave shuffle reduction for the loss (no barriers)
  float s = d0 * d0 + d1 * d1 + d2 * d2 + d3 * d3;
#pragma unroll
  for (int o = 32; o > 0; o >>= 1) s += __shfl_down(s, o);
  if ((threadIdx.x & 63) == 0) unsafeAtomicAdd(loss_acc, (double)s);

  float* dst = dwe + (size_t)k * DDIM + 4 * j;
  unsafeAtomicAdd(dst + 0, xv.x);
  unsafeAtomicAdd(dst + 1, xv.y);
  unsafeAtomicAdd(dst + 2, xv.z);
  unsafeAtomicAdd(dst + 3, xv.w);
  if (j == 0) unsafeAtomicAdd(&dw[k], 1.0f);
}

// ---------------- kernel: cluster-size EMA, n-sum, smoothing, loss ----------------
__global__ __launch_bounds__(1024) void k_final1(const float* __restrict__ cs,
                                                 const float* __restrict__ dw,
                                                 float* __restrict__ out_ncs,
                                                 float* __restrict__ smoothed,
                                                 const double* __restrict__ loss_acc,
                                                 float* __restrict__ out_loss) {
#pragma clang fp contract(off)
  __shared__ float red[1024];
  int t = threadIdx.x;
  float p0 = cs[t] * DECAYF;
  float p1 = cs[t + 1024] * DECAYF;
  float w0 = OMDF * dw[t];
  float w1 = OMDF * dw[t + 1024];
  float ncs0 = p0 + w0;
  float ncs1 = p1 + w1;
  out_ncs[t] = ncs0;
  out_ncs[t + 1024] = ncs1;
  red[t] = ncs0 + ncs1;
  __syncthreads();
  for (int o = 512; o > 0; o >>= 1) {
    if (t < o) red[t] += red[t + o];
    __syncthreads();
  }
  float nsum = red[0];
  smoothed[t] = (ncs0 + EPSF) / (nsum + KEPSF) * nsum;
  smoothed[t + 1024] = (ncs1 + EPSF) / (nsum + KEPSF) * nsum;
  if (t == 0) {
    float m = (float)(loss_acc[0] / (double)((size_t)NROWS * DDIM));
    out_loss[0] = m + 1.0f * m;
  }
}

// ---------------- kernel: embed_avg EMA + new embedding ----------------
__global__ __launch_bounds__(256) void k_final2(const float* __restrict__ ea,
                                                const float* __restrict__ dwe,
                                                const float* __restrict__ smoothed,
                                                float* __restrict__ out_ne,
                                                float* __restrict__ out_nea) {
#pragma clang fp contract(off)
  int i = blockIdx.x * 256 + threadIdx.x;
  float p = ea[i] * DECAYF;
  float w = OMDF * dwe[i];
  float nea = p + w;
  out_nea[i] = nea;
  out_ne[i] = nea / smoothed[i >> 7];
}

extern "C" void kernel_launch(void* const* d_in, const int* in_sizes, int n_in,
                              void* d_out, int out_size, void* d_ws, size_t ws_size,
                              hipStream_t stream) {
  const float* x   = (const float*)d_in[0];
  const float* emb = (const float*)d_in[1];
  const float* cs  = (const float*)d_in[2];
  const float* ea  = (const float*)d_in[3];

  float* out = (float*)d_out;
  float* out_q    = out;            // [N*D]
  float* out_loss = out + 8388608;  // [1]
  float* out_idx  = out + 8388609;  // [N] (float-encoded ints)
  float* out_ne   = out + 8454145;  // [K*D]
  float* out_ncs  = out + 8716289;  // [K]
  float* out_nea  = out + 8718337;  // [K*D]

  char* ws = (char*)d_ws;
  unsigned short* ehi = (unsigned short*)(ws + 0);        // 512 KB
  unsigned short* elo = (unsigned short*)(ws + 524288);   // 512 KB
  int*    idx      = (int*)(ws + 1048576);                // 256 KB
  int*    flaglist = (int*)(ws + 1310720);                // 256 KB
  float*  dwe      = (float*)(ws + 1572864);              // 1 MB
  float*  dw       = (float*)(ws + 2621440);              // 8 KB
  float*  se       = (float*)(ws + 2629632);              // 8 KB
  float*  smoothed = (float*)(ws + 2637824);              // 8 KB
  double* loss_acc = (double*)(ws + 2646016);             // 8 B
  int*    flagcnt  = (int*)(ws + 2646024);                // 4 B

  hipMemsetAsync(ws + 1572864, 0, 1048576 + 8192, stream);  // dwe + dw
  hipMemsetAsync(ws + 2646016, 0, 12, stream);              // loss_acc + flagcnt

  k_split<<<(KCODE * DDIM) / 256, 256, 0, stream>>>(emb, ehi, elo);
  k_sumsq_emb<<<(KCODE + 255) / 256, 256, 0, stream>>>(emb, se);
  k_screen<<<NROWS / 128, 256, 0, stream>>>(x, ehi, elo, se, out_idx, idx, flaglist, flagcnt);
  k_exact<<<2048, 64, 0, stream>>>(x, emb, se, flaglist, flagcnt, idx, out_idx);
  k_quant<<<(NROWS * 32) / 256, 256, 0, stream>>>(x, emb, idx, out_q, dw, dwe, loss_acc);
  k_final1<<<1, 1024, 0, stream>>>(cs, dw, out_ncs, smoothed, loss_acc, out_loss);
  k_final2<<<(KCODE * DDIM) / 256, 256, 0, stream>>>(ea, dwe, smoothed, out_ne, out_nea);
}

// Round 9
// 408.037 us; speedup vs baseline: 1.9329x; 1.9329x over previous
//
#include <hip/hip_runtime.h>

#define NROWS 65536
#define KCODE 2048
#define DDIM  128

static constexpr float DECAYF = 0.99f;
static constexpr float OMDF   = (float)(1.0 - 0.99);
static constexpr float EPSF   = 1e-5f;
static constexpr float KEPSF  = (float)(2048.0 * 1e-5);
static constexpr float MARGIN = 1e-3f;

typedef __attribute__((ext_vector_type(8))) short bf16x8;
typedef __attribute__((ext_vector_type(4))) float f32x4;

__device__ __forceinline__ unsigned int bf16_rne_bits(float f) {
  unsigned int u = __builtin_bit_cast(unsigned int, f);
  return (u + 0x7fffu + ((u >> 16) & 1u)) >> 16;
}

// ---------------- kernel: split codebook into bf16 hi/lo planes ----------------
__global__ __launch_bounds__(256) void k_split(const float* __restrict__ emb,
                                               unsigned short* __restrict__ ehi,
                                               unsigned short* __restrict__ elo) {
  int i = blockIdx.x * 256 + threadIdx.x;
  float f = emb[i];
  unsigned int hr = bf16_rne_bits(f);
  float hif = __builtin_bit_cast(float, hr << 16);
  float lo = f - hif;                    // exact (Sterbenz)
  unsigned int lr = bf16_rne_bits(lo);
  ehi[i] = (unsigned short)hr;
  elo[i] = (unsigned short)lr;
}

// ---------------- kernel: per-code sum of squares (exact ref order) ----------------
__global__ __launch_bounds__(256) void k_sumsq_emb(const float* __restrict__ emb,
                                                   float* __restrict__ se) {
#pragma clang fp contract(off)
  int k = blockIdx.x * 256 + threadIdx.x;
  if (k >= KCODE) return;
  const float* row = emb + (size_t)k * DDIM;
  float s = 0.f;
#pragma unroll
  for (int d = 0; d < DDIM; ++d) {
    float q = row[d] * row[d];
    s = s + q;
  }
  se[k] = s;
}

// ---------------- kernel: MFMA screen, LDS-staged codebook (unchanged r6) ----------------
__global__ __launch_bounds__(256, 2) void k_screen(
    const float* __restrict__ x, const unsigned short* __restrict__ ehi,
    const unsigned short* __restrict__ elo, const float* __restrict__ se,
    float* __restrict__ out_idxf, int* __restrict__ idx,
    int* __restrict__ flaglist, int* __restrict__ flagcnt) {
  const int tid = threadIdx.x;
  const int lane = tid & 63;
  const int wid = tid >> 6;
  const int rowbase = (blockIdx.x * 4 + wid) * 32;
  const int l15 = lane & 15, l4 = lane >> 4;

  __shared__ __align__(16) char lds[2][8192];
  char* lbase = &lds[0][0];

  bf16x8 ahi0[4], alo0[4], ahi1[4], alo1[4];
#pragma unroll
  for (int t = 0; t < 2; ++t) {
#pragma unroll
    for (int f = 0; f < 4; ++f) {
      const float4* s4 =
          (const float4*)(x + (size_t)(rowbase + t * 16 + l15) * DDIM + f * 32 + l4 * 8);
      float4 v0 = s4[0], v1 = s4[1];
      float fv[8] = {v0.x, v0.y, v0.z, v0.w, v1.x, v1.y, v1.z, v1.w};
      union { unsigned short u[8]; bf16x8 v; } H, L;
#pragma unroll
      for (int j = 0; j < 8; ++j) {
        unsigned int hr = bf16_rne_bits(fv[j]);
        float hif = __builtin_bit_cast(float, hr << 16);
        unsigned int lr = bf16_rne_bits(fv[j] - hif);
        H.u[j] = (unsigned short)hr;
        L.u[j] = (unsigned short)lr;
      }
      if (t == 0) { ahi0[f] = H.v; alo0[f] = L.v; }
      else        { ahi1[f] = H.v; alo1[f] = L.v; }
    }
  }

  int raddr[2][4];
#pragma unroll
  for (int p = 0; p < 2; ++p)
#pragma unroll
    for (int f = 0; f < 4; ++f)
      raddr[p][f] = p * 4096 + ((l15 * 256 + f * 64 + l4 * 16) ^ ((l15 & 7) << 4));

  const unsigned short* splane = (tid & 128) ? elo : ehi;
  const int po0 = (tid & 127) * 32;
  const char* sp = (const char*)splane + po0;
  const int wplane = (tid >> 7) * 4096;
  const int waddr0 = wplane + (po0 ^ (((po0 >> 8) & 7) << 4));
  const int waddr1 = wplane + ((po0 + 16) ^ ((((po0 + 16) >> 8) & 7) << 4));

  float m1[8], m2[8];
  int k1[8];
#pragma unroll
  for (int s = 0; s < 8; ++s) { m1[s] = INFINITY; m2[s] = INFINITY; k1[s] = 0; }

  {
    int4 v0 = *(const int4*)(sp);
    int4 v1 = *(const int4*)(sp + 16);
    *(int4*)(lbase + waddr0) = v0;
    *(int4*)(lbase + waddr1) = v1;
  }
  __syncthreads();

  int bufoff = 0;
#pragma unroll 2
  for (int g = 0; g < 128; ++g) {
    float sec = se[g * 16 + l15];
    int4 nv0, nv1;
    if (g < 127) {
      nv0 = *(const int4*)(sp + (size_t)(g + 1) * 4096);
      nv1 = *(const int4*)(sp + (size_t)(g + 1) * 4096 + 16);
    }
    f32x4 hh0 = {0.f, 0.f, 0.f, 0.f}, hl0 = {0.f, 0.f, 0.f, 0.f}, lh0 = {0.f, 0.f, 0.f, 0.f};
    f32x4 hh1 = {0.f, 0.f, 0.f, 0.f}, hl1 = {0.f, 0.f, 0.f, 0.f}, lh1 = {0.f, 0.f, 0.f, 0.f};
#pragma unroll
    for (int f = 0; f < 4; ++f) {
      bf16x8 BH = *(const bf16x8*)(lbase + bufoff + raddr[0][f]);
      bf16x8 BL = *(const bf16x8*)(lbase + bufoff + raddr[1][f]);
      hh0 = __builtin_amdgcn_mfma_f32_16x16x32_bf16(ahi0[f], BH, hh0, 0, 0, 0);
      lh0 = __builtin_amdgcn_mfma_f32_16x16x32_bf16(alo0[f], BH, lh0, 0, 0, 0);
      hl0 = __builtin_amdgcn_mfma_f32_16x16x32_bf16(ahi0[f], BL, hl0, 0, 0, 0);
      hh1 = __builtin_amdgcn_mfma_f32_16x16x32_bf16(ahi1[f], BH, hh1, 0, 0, 0);
      lh1 = __builtin_amdgcn_mfma_f32_16x16x32_bf16(alo1[f], BH, lh1, 0, 0, 0);
      hl1 = __builtin_amdgcn_mfma_f32_16x16x32_bf16(ahi1[f], BL, hl1, 0, 0, 0);
    }
    int c_ = g * 16 + l15;
#pragma unroll
    for (int s = 0; s < 4; ++s) {
      float vv = fmaf(-2.f, (hh0[s] + hl0[s]) + lh0[s], sec);
      m2[s] = fminf(m2[s], fmaxf(vv, m1[s]));
      k1[s] = (vv < m1[s]) ? c_ : k1[s];
      m1[s] = fminf(m1[s], vv);
      float vw = fmaf(-2.f, (hh1[s] + hl1[s]) + lh1[s], sec);
      m2[s + 4] = fminf(m2[s + 4], fmaxf(vw, m1[s + 4]));
      k1[s + 4] = (vw < m1[s + 4]) ? c_ : k1[s + 4];
      m1[s + 4] = fminf(m1[s + 4], vw);
    }
    if (g < 127) {
      *(int4*)(lbase + (bufoff ^ 8192) + waddr0) = nv0;
      *(int4*)(lbase + (bufoff ^ 8192) + waddr1) = nv1;
    }
    __syncthreads();
    bufoff ^= 8192;
  }

#pragma unroll
  for (int off = 1; off < 16; off <<= 1) {
#pragma unroll
    for (int s = 0; s < 8; ++s) {
      float om1 = __shfl_xor(m1[s], off);
      float om2 = __shfl_xor(m2[s], off);
      int ok1 = __shfl_xor(k1[s], off);
      m2[s] = fminf(fminf(m2[s], om2), fmaxf(m1[s], om1));
      k1[s] = (om1 < m1[s]) ? ok1 : k1[s];
      m1[s] = fminf(m1[s], om1);
    }
  }
  if (l15 == 0) {
#pragma unroll
    for (int s = 0; s < 8; ++s) {
      int row = rowbase + (s >> 2) * 16 + l4 * 4 + (s & 3);
      idx[row] = k1[s];
      out_idxf[row] = (float)k1[s];
      if (m2[s] - m1[s] <= MARGIN) {
        int p = atomicAdd(flagcnt, 1);
        if (p < NROWS) flaglist[p] = row;
      }
    }
  }
}

// ---------------- kernel: exact re-rank of flagged rows (unchanged) ----------------
__global__ __launch_bounds__(64) void k_exact(
    const float* __restrict__ x, const float* __restrict__ emb,
    const float* __restrict__ se, const int* __restrict__ flaglist,
    const int* __restrict__ flagcnt, int* __restrict__ idx,
    float* __restrict__ out_idxf) {
#pragma clang fp contract(off)
  int cnt = *flagcnt;
  if (cnt > NROWS) cnt = NROWS;
  int lane = threadIdx.x;
  for (int i = blockIdx.x; i < cnt; i += gridDim.x) {
    int row = flaglist[i];
    const float4* xp = (const float4*)(x + (size_t)row * DDIM);
    float4 xr[32];
#pragma unroll
    for (int j = 0; j < 32; ++j) xr[j] = xp[j];
    float sx = 0.f;
#pragma unroll
    for (int j = 0; j < 32; ++j) {
      float q0 = xr[j].x * xr[j].x; sx = sx + q0;
      float q1 = xr[j].y * xr[j].y; sx = sx + q1;
      float q2 = xr[j].z * xr[j].z; sx = sx + q2;
      float q3 = xr[j].w * xr[j].w; sx = sx + q3;
    }
    float bestd = INFINITY;
    int bestk = lane * 32;
    for (int cb = 0; cb < 32; cb += 4) {
      float c4[4] = {0.f, 0.f, 0.f, 0.f};
#pragma unroll
      for (int d4 = 0; d4 < 32; ++d4) {
#pragma unroll
        for (int u = 0; u < 4; ++u) {
          float4 e = ((const float4*)(emb + (size_t)(lane * 32 + cb + u) * DDIM))[d4];
          c4[u] = fmaf(e.x, xr[d4].x, c4[u]);
          c4[u] = fmaf(e.y, xr[d4].y, c4[u]);
          c4[u] = fmaf(e.z, xr[d4].z, c4[u]);
          c4[u] = fmaf(e.w, xr[d4].w, c4[u]);
        }
      }
#pragma unroll
      for (int u = 0; u < 4; ++u) {
        int c = lane * 32 + cb + u;
        float t = sx + se[c];
        float tw = 2.0f * c4[u];
        float d = t - tw;
        if (d < bestd) { bestd = d; bestk = c; }
      }
    }
#pragma unroll
    for (int off = 1; off < 64; off <<= 1) {
      float od = __shfl_xor(bestd, off);
      int ok = __shfl_xor(bestk, off);
      if (od < bestd || (od == bestd && ok < bestk)) { bestd = od; bestk = ok; }
    }
    if (lane == 0) { idx[row] = bestk; out_idxf[row] = (float)bestk; }
  }
}

// ---------------- kernel: histogram of final indices ----------------
__global__ __launch_bounds__(256) void k_hist(const int* __restrict__ idx,
                                              int* __restrict__ cnt) {
  int n = blockIdx.x * 256 + threadIdx.x;
  atomicAdd(&cnt[idx[n]], 1);
}

// ---------------- kernel: one-block exclusive scan over 2048 counts ----------------
__global__ __launch_bounds__(1024) void k_scan(const int* __restrict__ cnt,
                                               int* __restrict__ off,
                                               int* __restrict__ pos_ctr,
                                               float* __restrict__ dwf) {
  __shared__ int sA[2048], sB[2048];
  int t = threadIdx.x;
  int c0 = cnt[t], c1 = cnt[t + 1024];
  sA[t] = c0; sA[t + 1024] = c1;
  __syncthreads();
  int* src = sA; int* dst = sB;
  for (int o = 1; o < 2048; o <<= 1) {
    int v0 = src[t] + ((t >= o) ? src[t - o] : 0);
    int p1 = t + 1024;
    int v1 = src[p1] + ((p1 >= o) ? src[p1 - o] : 0);
    dst[t] = v0; dst[p1] = v1;
    __syncthreads();
    int* tmp = src; src = dst; dst = tmp;
  }
  int e0 = src[t] - c0;
  int e1 = src[t + 1024] - c1;
  off[t] = e0; off[t + 1024] = e1;
  pos_ctr[t] = e0; pos_ctr[t + 1024] = e1;
  dwf[t] = (float)c0; dwf[t + 1024] = (float)c1;  // exact int->f32
}

// ---------------- kernel: scatter row ids into buckets ----------------
__global__ __launch_bounds__(256) void k_scatter(const int* __restrict__ idx,
                                                 int* __restrict__ pos_ctr,
                                                 int* __restrict__ rowlist) {
  int n = blockIdx.x * 256 + threadIdx.x;
  int k = idx[n];
  int p = atomicAdd(&pos_ctr[k], 1);
  rowlist[p] = n;
}

// ---------------- kernel: per-code gather segment-sum (no atomics) ----------------
__global__ __launch_bounds__(128) void k_dwe(const float* __restrict__ x,
                                             const int* __restrict__ rowlist,
                                             const int* __restrict__ cnt,
                                             const int* __restrict__ off,
                                             float* __restrict__ dwe) {
  int k = blockIdx.x, d = threadIdx.x;
  int n = cnt[k], base = off[k];
  float s0 = 0.f, s1 = 0.f, s2 = 0.f, s3 = 0.f;
  int i = 0;
  for (; i + 4 <= n; i += 4) {
    int r0 = rowlist[base + i + 0];
    int r1 = rowlist[base + i + 1];
    int r2 = rowlist[base + i + 2];
    int r3 = rowlist[base + i + 3];
    s0 += x[(size_t)r0 * DDIM + d];
    s1 += x[(size_t)r1 * DDIM + d];
    s2 += x[(size_t)r2 * DDIM + d];
    s3 += x[(size_t)r3 * DDIM + d];
  }
  for (; i < n; ++i) {
    int r = rowlist[base + i];
    s0 += x[(size_t)r * DDIM + d];
  }
  dwe[(size_t)k * DDIM + d] = (s0 + s1) + (s2 + s3);
}

// ------- kernel: gather/quantize + ST output + loss partials (no atomics) -------
__global__ __launch_bounds__(256) void k_quant2(const float* __restrict__ x,
                                                const float* __restrict__ emb,
                                                const int* __restrict__ idx,
                                                float* __restrict__ out_q,
                                                double* __restrict__ partial_loss) {
#pragma clang fp contract(off)
  int t = blockIdx.x * 256 + threadIdx.x;
  int n = t >> 5, j = t & 31;
  int k = idx[n];
  float4 xv = ((const float4*)(x + (size_t)n * DDIM))[j];
  float4 ev = ((const float4*)(emb + (size_t)k * DDIM))[j];
  float d0 = ev.x - xv.x, d1 = ev.y - xv.y, d2 = ev.z - xv.z, d3 = ev.w - xv.w;
  float4 q;
  q.x = xv.x + d0; q.y = xv.y + d1; q.z = xv.z + d2; q.w = xv.w + d3;
  ((float4*)(out_q + (size_t)n * DDIM))[j] = q;

  float s = d0 * d0 + d1 * d1 + d2 * d2 + d3 * d3;
#pragma unroll
  for (int o = 32; o > 0; o >>= 1) s += __shfl_down(s, o);
  __shared__ float wsum[4];
  if ((threadIdx.x & 63) == 0) wsum[threadIdx.x >> 6] = s;
  __syncthreads();
  if (threadIdx.x == 0)
    partial_loss[blockIdx.x] =
        (double)((wsum[0] + wsum[1]) + (wsum[2] + wsum[3]));
}

// ---------------- kernel: cluster-size EMA, n-sum, smoothing, loss ----------------
__global__ __launch_bounds__(1024) void k_final1(const float* __restrict__ cs,
                                                 const float* __restrict__ dwf,
                                                 float* __restrict__ out_ncs,
                                                 float* __restrict__ smoothed,
                                                 const double* __restrict__ partial_loss,
                                                 float* __restrict__ out_loss) {
#pragma clang fp contract(off)
  __shared__ float red[1024];
  __shared__ double dred[1024];
  int t = threadIdx.x;
  float p0 = cs[t] * DECAYF;
  float p1 = cs[t + 1024] * DECAYF;
  float w0 = OMDF * dwf[t];
  float w1 = OMDF * dwf[t + 1024];
  float ncs0 = p0 + w0;
  float ncs1 = p1 + w1;
  out_ncs[t] = ncs0;
  out_ncs[t + 1024] = ncs1;
  red[t] = ncs0 + ncs1;
  double ds = 0.0;
#pragma unroll
  for (int i = 0; i < 8; ++i) ds += partial_loss[t + i * 1024];
  dred[t] = ds;
  __syncthreads();
  for (int o = 512; o > 0; o >>= 1) {
    if (t < o) { red[t] += red[t + o]; dred[t] += dred[t + o]; }
    __syncthreads();
  }
  float nsum = red[0];
  smoothed[t] = (ncs0 + EPSF) / (nsum + KEPSF) * nsum;
  smoothed[t + 1024] = (ncs1 + EPSF) / (nsum + KEPSF) * nsum;
  if (t == 0) {
    float m = (float)(dred[0] / (double)((size_t)NROWS * DDIM));
    out_loss[0] = m + 1.0f * m;
  }
}

// ---------------- kernel: embed_avg EMA + new embedding ----------------
__global__ __launch_bounds__(256) void k_final2(const float* __restrict__ ea,
                                                const float* __restrict__ dwe,
                                                const float* __restrict__ smoothed,
                                                float* __restrict__ out_ne,
                                                float* __restrict__ out_nea) {
#pragma clang fp contract(off)
  int i = blockIdx.x * 256 + threadIdx.x;
  float p = ea[i] * DECAYF;
  float w = OMDF * dwe[i];
  float nea = p + w;
  out_nea[i] = nea;
  out_ne[i] = nea / smoothed[i >> 7];
}

extern "C" void kernel_launch(void* const* d_in, const int* in_sizes, int n_in,
                              void* d_out, int out_size, void* d_ws, size_t ws_size,
                              hipStream_t stream) {
  const float* x   = (const float*)d_in[0];
  const float* emb = (const float*)d_in[1];
  const float* cs  = (const float*)d_in[2];
  const float* ea  = (const float*)d_in[3];

  float* out = (float*)d_out;
  float* out_q    = out;            // [N*D]
  float* out_loss = out + 8388608;  // [1]
  float* out_idx  = out + 8388609;  // [N] (float-encoded ints)
  float* out_ne   = out + 8454145;  // [K*D]
  float* out_ncs  = out + 8716289;  // [K]
  float* out_nea  = out + 8718337;  // [K*D]

  char* ws = (char*)d_ws;
  unsigned short* ehi = (unsigned short*)(ws + 0);         // 512 KB
  unsigned short* elo = (unsigned short*)(ws + 524288);    // 512 KB
  int*    idx      = (int*)(ws + 1048576);                 // 256 KB
  int*    flaglist = (int*)(ws + 1310720);                 // 256 KB
  int*    rowlist  = (int*)(ws + 1572864);                 // 256 KB
  int*    cnt      = (int*)(ws + 1835008);                 // 8 KB
  int*    flagcnt  = (int*)(ws + 1843200);                 // 64 B (padded)
  int*    pos_ctr  = (int*)(ws + 1843264);                 // 8 KB
  int*    off      = (int*)(ws + 1851456);                 // 8 KB
  float*  dwf      = (float*)(ws + 1859648);               // 8 KB
  float*  se       = (float*)(ws + 1867840);               // 8 KB
  float*  smoothed = (float*)(ws + 1876032);               // 8 KB
  float*  dwe      = (float*)(ws + 1884224);               // 1 MB
  double* partial_loss = (double*)(ws + 2932800);          // 64 KB (8192 doubles)

  // zero only histogram + flag counter (everything else fully overwritten)
  hipMemsetAsync(ws + 1835008, 0, 8192 + 64, stream);

  k_split<<<(KCODE * DDIM) / 256, 256, 0, stream>>>(emb, ehi, elo);
  k_sumsq_emb<<<(KCODE + 255) / 256, 256, 0, stream>>>(emb, se);
  k_screen<<<NROWS / 128, 256, 0, stream>>>(x, ehi, elo, se, out_idx, idx, flaglist, flagcnt);
  k_exact<<<2048, 64, 0, stream>>>(x, emb, se, flaglist, flagcnt, idx, out_idx);
  k_hist<<<NROWS / 256, 256, 0, stream>>>(idx, cnt);
  k_scan<<<1, 1024, 0, stream>>>(cnt, off, pos_ctr, dwf);
  k_scatter<<<NROWS / 256, 256, 0, stream>>>(idx, pos_ctr, rowlist);
  k_dwe<<<KCODE, 128, 0, stream>>>(x, rowlist, cnt, off, dwe);
  k_quant2<<<(NROWS * 32) / 256, 256, 0, stream>>>(x, emb, idx, out_q, partial_loss);
  k_final1<<<1, 1024, 0, stream>>>(cs, dwf, out_ncs, smoothed, partial_loss, out_loss);
  k_final2<<<(KCODE * DDIM) / 256, 256, 0, stream>>>(ea, dwe, smoothed, out_ne, out_nea);
}

// Round 11
// 402.220 us; speedup vs baseline: 1.9608x; 1.0145x over previous
//
#include <hip/hip_runtime.h>

#define NROWS 65536
#define KCODE 2048
#define DDIM  128

static constexpr float DECAYF = 0.99f;
static constexpr float OMDF   = (float)(1.0 - 0.99);
static constexpr float EPSF   = 1e-5f;
static constexpr float KEPSF  = (float)(2048.0 * 1e-5);
static constexpr float MARGIN = 1e-3f;

typedef __attribute__((ext_vector_type(8))) short bf16x8;
typedef __attribute__((ext_vector_type(4))) float f32x4;

__device__ __forceinline__ unsigned int bf16_rne_bits(float f) {
  unsigned int u = __builtin_bit_cast(unsigned int, f);
  return (u + 0x7fffu + ((u >> 16) & 1u)) >> 16;
}

// ---------------- kernel: split codebook into bf16 hi/lo planes ----------------
__global__ __launch_bounds__(256) void k_split(const float* __restrict__ emb,
                                               unsigned short* __restrict__ ehi,
                                               unsigned short* __restrict__ elo) {
  int i = blockIdx.x * 256 + threadIdx.x;
  float f = emb[i];
  unsigned int hr = bf16_rne_bits(f);
  float hif = __builtin_bit_cast(float, hr << 16);
  float lo = f - hif;                    // exact (Sterbenz)
  unsigned int lr = bf16_rne_bits(lo);
  ehi[i] = (unsigned short)hr;
  elo[i] = (unsigned short)lr;
}

// ---------------- kernel: per-code sum of squares (exact ref order) ----------------
__global__ __launch_bounds__(256) void k_sumsq_emb(const float* __restrict__ emb,
                                                   float* __restrict__ se) {
#pragma clang fp contract(off)
  int k = blockIdx.x * 256 + threadIdx.x;
  if (k >= KCODE) return;
  const float* row = emb + (size_t)k * DDIM;
  float s = 0.f;
#pragma unroll
  for (int d = 0; d < DDIM; ++d) {
    float q = row[d] * row[d];
    s = s + q;
  }
  se[k] = s;
}

// ---------------- kernel: MFMA screen, LDS-staged codebook (unchanged r6) ----------------
__global__ __launch_bounds__(256, 2) void k_screen(
    const float* __restrict__ x, const unsigned short* __restrict__ ehi,
    const unsigned short* __restrict__ elo, const float* __restrict__ se,
    float* __restrict__ out_idxf, int* __restrict__ idx,
    int* __restrict__ flaglist, int* __restrict__ flagcnt) {
  const int tid = threadIdx.x;
  const int lane = tid & 63;
  const int wid = tid >> 6;
  const int rowbase = (blockIdx.x * 4 + wid) * 32;
  const int l15 = lane & 15, l4 = lane >> 4;

  __shared__ __align__(16) char lds[2][8192];
  char* lbase = &lds[0][0];

  bf16x8 ahi0[4], alo0[4], ahi1[4], alo1[4];
#pragma unroll
  for (int t = 0; t < 2; ++t) {
#pragma unroll
    for (int f = 0; f < 4; ++f) {
      const float4* s4 =
          (const float4*)(x + (size_t)(rowbase + t * 16 + l15) * DDIM + f * 32 + l4 * 8);
      float4 v0 = s4[0], v1 = s4[1];
      float fv[8] = {v0.x, v0.y, v0.z, v0.w, v1.x, v1.y, v1.z, v1.w};
      union { unsigned short u[8]; bf16x8 v; } H, L;
#pragma unroll
      for (int j = 0; j < 8; ++j) {
        unsigned int hr = bf16_rne_bits(fv[j]);
        float hif = __builtin_bit_cast(float, hr << 16);
        unsigned int lr = bf16_rne_bits(fv[j] - hif);
        H.u[j] = (unsigned short)hr;
        L.u[j] = (unsigned short)lr;
      }
      if (t == 0) { ahi0[f] = H.v; alo0[f] = L.v; }
      else        { ahi1[f] = H.v; alo1[f] = L.v; }
    }
  }

  int raddr[2][4];
#pragma unroll
  for (int p = 0; p < 2; ++p)
#pragma unroll
    for (int f = 0; f < 4; ++f)
      raddr[p][f] = p * 4096 + ((l15 * 256 + f * 64 + l4 * 16) ^ ((l15 & 7) << 4));

  const unsigned short* splane = (tid & 128) ? elo : ehi;
  const int po0 = (tid & 127) * 32;
  const char* sp = (const char*)splane + po0;
  const int wplane = (tid >> 7) * 4096;
  const int waddr0 = wplane + (po0 ^ (((po0 >> 8) & 7) << 4));
  const int waddr1 = wplane + ((po0 + 16) ^ ((((po0 + 16) >> 8) & 7) << 4));

  float m1[8], m2[8];
  int k1[8];
#pragma unroll
  for (int s = 0; s < 8; ++s) { m1[s] = INFINITY; m2[s] = INFINITY; k1[s] = 0; }

  {
    int4 v0 = *(const int4*)(sp);
    int4 v1 = *(const int4*)(sp + 16);
    *(int4*)(lbase + waddr0) = v0;
    *(int4*)(lbase + waddr1) = v1;
  }
  __syncthreads();

  int bufoff = 0;
#pragma unroll 2
  for (int g = 0; g < 128; ++g) {
    float sec = se[g * 16 + l15];
    int4 nv0, nv1;
    if (g < 127) {
      nv0 = *(const int4*)(sp + (size_t)(g + 1) * 4096);
      nv1 = *(const int4*)(sp + (size_t)(g + 1) * 4096 + 16);
    }
    f32x4 hh0 = {0.f, 0.f, 0.f, 0.f}, hl0 = {0.f, 0.f, 0.f, 0.f}, lh0 = {0.f, 0.f, 0.f, 0.f};
    f32x4 hh1 = {0.f, 0.f, 0.f, 0.f}, hl1 = {0.f, 0.f, 0.f, 0.f}, lh1 = {0.f, 0.f, 0.f, 0.f};
#pragma unroll
    for (int f = 0; f < 4; ++f) {
      bf16x8 BH = *(const bf16x8*)(lbase + bufoff + raddr[0][f]);
      bf16x8 BL = *(const bf16x8*)(lbase + bufoff + raddr[1][f]);
      hh0 = __builtin_amdgcn_mfma_f32_16x16x32_bf16(ahi0[f], BH, hh0, 0, 0, 0);
      lh0 = __builtin_amdgcn_mfma_f32_16x16x32_bf16(alo0[f], BH, lh0, 0, 0, 0);
      hl0 = __builtin_amdgcn_mfma_f32_16x16x32_bf16(ahi0[f], BL, hl0, 0, 0, 0);
      hh1 = __builtin_amdgcn_mfma_f32_16x16x32_bf16(ahi1[f], BH, hh1, 0, 0, 0);
      lh1 = __builtin_amdgcn_mfma_f32_16x16x32_bf16(alo1[f], BH, lh1, 0, 0, 0);
      hl1 = __builtin_amdgcn_mfma_f32_16x16x32_bf16(ahi1[f], BL, hl1, 0, 0, 0);
    }
    int c_ = g * 16 + l15;
#pragma unroll
    for (int s = 0; s < 4; ++s) {
      float vv = fmaf(-2.f, (hh0[s] + hl0[s]) + lh0[s], sec);
      m2[s] = fminf(m2[s], fmaxf(vv, m1[s]));
      k1[s] = (vv < m1[s]) ? c_ : k1[s];
      m1[s] = fminf(m1[s], vv);
      float vw = fmaf(-2.f, (hh1[s] + hl1[s]) + lh1[s], sec);
      m2[s + 4] = fminf(m2[s + 4], fmaxf(vw, m1[s + 4]));
      k1[s + 4] = (vw < m1[s + 4]) ? c_ : k1[s + 4];
      m1[s + 4] = fminf(m1[s + 4], vw);
    }
    if (g < 127) {
      *(int4*)(lbase + (bufoff ^ 8192) + waddr0) = nv0;
      *(int4*)(lbase + (bufoff ^ 8192) + waddr1) = nv1;
    }
    __syncthreads();
    bufoff ^= 8192;
  }

#pragma unroll
  for (int off = 1; off < 16; off <<= 1) {
#pragma unroll
    for (int s = 0; s < 8; ++s) {
      float om1 = __shfl_xor(m1[s], off);
      float om2 = __shfl_xor(m2[s], off);
      int ok1 = __shfl_xor(k1[s], off);
      m2[s] = fminf(fminf(m2[s], om2), fmaxf(m1[s], om1));
      k1[s] = (om1 < m1[s]) ? ok1 : k1[s];
      m1[s] = fminf(m1[s], om1);
    }
  }
  if (l15 == 0) {
#pragma unroll
    for (int s = 0; s < 8; ++s) {
      int row = rowbase + (s >> 2) * 16 + l4 * 4 + (s & 3);
      idx[row] = k1[s];
      out_idxf[row] = (float)k1[s];
      if (m2[s] - m1[s] <= MARGIN) {
        int p = atomicAdd(flagcnt, 1);
        if (p < NROWS) flaglist[p] = row;
      }
    }
  }
}

// ---------------- kernel: exact re-rank, cooperative tiled version ----------------
// Block = 256 threads, 16 flagged rows per iteration. Codebook scanned in 32
// tiles of 64 codes staged f32 in LDS with slot^=(code&31) swizzle (2-way max).
// Lane owns 1 code x 4 rows: e-read amortized 4x, x via LDS broadcast.
// Per (row,code): strictly sequential-d FMA chain + fl((sx+se)-2*dot),
// first-occurrence argmin (ascending tiles per lane; tie -> lower code) ==
// reference semantics, bit-exact.
__global__ __launch_bounds__(256) void k_exact(
    const float* __restrict__ x, const float* __restrict__ emb,
    const float* __restrict__ se, const int* __restrict__ flaglist,
    const int* __restrict__ flagcnt, int* __restrict__ idx,
    float* __restrict__ out_idxf) {
#pragma clang fp contract(off)
  int cnt = *flagcnt;
  if (cnt > NROWS) cnt = NROWS;
  const int tid = threadIdx.x;
  const int lane = tid & 63;
  const int wv = tid >> 6;          // wave id = row group

  __shared__ __align__(16) float xs[16][128];  // 8 KB row stage
  __shared__ float sxs[16];
  __shared__ int rids[16];
  __shared__ __align__(16) float es[64 * 128]; // 32 KB code tile (swizzled)

  for (int base = blockIdx.x * 16; base < cnt; base += gridDim.x * 16) {
    int nrows = cnt - base; if (nrows > 16) nrows = 16;
    // barrier below (after rids write) also ensures all waves finished the
    // previous iteration's compute before xs/es are overwritten.
    if (tid < 16) rids[tid] = flaglist[base + ((tid < nrows) ? tid : 0)];
    __syncthreads();
    {
      int row = tid >> 4, off = (tid & 15) * 8;
      const float4* src = (const float4*)(x + (size_t)rids[row] * DDIM + off);
      float4 a = src[0], b = src[1];
      *(float4*)&xs[row][off] = a;
      *(float4*)&xs[row][off + 4] = b;
    }
    __syncthreads();
    if (tid < 16) {                 // exact sequential sum of rounded squares
      float s = 0.f;
      for (int d = 0; d < DDIM; ++d) { float q = xs[tid][d] * xs[tid][d]; s = s + q; }
      sxs[tid] = s;
    }
    __syncthreads();

    const int row0 = wv * 4;
    float sxr[4];
#pragma unroll
    for (int r = 0; r < 4; ++r) sxr[r] = sxs[row0 + r];

    float bestd[4]; int bestk[4];
#pragma unroll
    for (int r = 0; r < 4; ++r) { bestd[r] = INFINITY; bestk[r] = 0; }

    const int ct = tid >> 2;          // staging: code within tile
    const int d40 = (tid & 3) * 8;    // staging: first 16B chunk
    for (int tile = 0; tile < 32; ++tile) {
      // T14: issue next tile's global loads into registers first
      float4 ebuf[8];
      {
        const float4* esrc =
            (const float4*)(emb + ((size_t)(tile * 64 + ct)) * DDIM + d40 * 4);
#pragma unroll
        for (int j = 0; j < 8; ++j) ebuf[j] = esrc[j];
      }
      __syncthreads();                // all waves done reading previous tile
#pragma unroll
      for (int j = 0; j < 8; ++j) {
        int d4 = d40 + j;
        int slot = d4 ^ (ct & 31);
        *(float4*)&es[ct * 128 + slot * 4] = ebuf[j];
      }
      __syncthreads();                // tile staged

      float a0 = 0.f, a1 = 0.f, a2 = 0.f, a3 = 0.f;
#pragma unroll
      for (int d4 = 0; d4 < 32; ++d4) {
        int slot = d4 ^ (lane & 31);
        float4 e4 = *(const float4*)&es[lane * 128 + slot * 4];
        float4 x0 = *(const float4*)&xs[row0 + 0][d4 * 4];
        float4 x1 = *(const float4*)&xs[row0 + 1][d4 * 4];
        float4 x2 = *(const float4*)&xs[row0 + 2][d4 * 4];
        float4 x3 = *(const float4*)&xs[row0 + 3][d4 * 4];
        a0 = fmaf(e4.x, x0.x, a0); a0 = fmaf(e4.y, x0.y, a0);
        a0 = fmaf(e4.z, x0.z, a0); a0 = fmaf(e4.w, x0.w, a0);
        a1 = fmaf(e4.x, x1.x, a1); a1 = fmaf(e4.y, x1.y, a1);
        a1 = fmaf(e4.z, x1.z, a1); a1 = fmaf(e4.w, x1.w, a1);
        a2 = fmaf(e4.x, x2.x, a2); a2 = fmaf(e4.y, x2.y, a2);
        a2 = fmaf(e4.z, x2.z, a2); a2 = fmaf(e4.w, x2.w, a2);
        a3 = fmaf(e4.x, x3.x, a3); a3 = fmaf(e4.y, x3.y, a3);
        a3 = fmaf(e4.z, x3.z, a3); a3 = fmaf(e4.w, x3.w, a3);
      }
      int code = tile * 64 + lane;
      float sec = se[code];
      float acc[4] = {a0, a1, a2, a3};
#pragma unroll
      for (int r = 0; r < 4; ++r) {
        float t_ = sxr[r] + sec;      // rounded add
        float tw = 2.0f * acc[r];     // exact
        float d_ = t_ - tw;           // rounded sub
        if (d_ < bestd[r]) { bestd[r] = d_; bestk[r] = code; }
      }
    }

    // cross-lane combine (strict <, tie -> lower code = first occurrence)
#pragma unroll
    for (int off = 1; off < 64; off <<= 1) {
#pragma unroll
      for (int r = 0; r < 4; ++r) {
        float od = __shfl_xor(bestd[r], off);
        int ok = __shfl_xor(bestk[r], off);
        if (od < bestd[r] || (od == bestd[r] && ok < bestk[r])) {
          bestd[r] = od; bestk[r] = ok;
        }
      }
    }
    if (lane == 0) {
#pragma unroll
      for (int r = 0; r < 4; ++r) {
        if (row0 + r < nrows) {
          int rid = rids[row0 + r];
          idx[rid] = bestk[r];
          out_idxf[rid] = (float)bestk[r];
        }
      }
    }
  }
}

// ---------------- kernel: histogram of final indices ----------------
__global__ __launch_bounds__(256) void k_hist(const int* __restrict__ idx,
                                              int* __restrict__ cnt) {
  int n = blockIdx.x * 256 + threadIdx.x;
  atomicAdd(&cnt[idx[n]], 1);
}

// ---------------- kernel: one-block exclusive scan over 2048 counts ----------------
__global__ __launch_bounds__(1024) void k_scan(const int* __restrict__ cnt,
                                               int* __restrict__ off,
                                               int* __restrict__ pos_ctr,
                                               float* __restrict__ dwf) {
  __shared__ int sA[2048], sB[2048];
  int t = threadIdx.x;
  int c0 = cnt[t], c1 = cnt[t + 1024];
  sA[t] = c0; sA[t + 1024] = c1;
  __syncthreads();
  int* src = sA; int* dst = sB;
  for (int o = 1; o < 2048; o <<= 1) {
    int v0 = src[t] + ((t >= o) ? src[t - o] : 0);
    int p1 = t + 1024;
    int v1 = src[p1] + ((p1 >= o) ? src[p1 - o] : 0);
    dst[t] = v0; dst[p1] = v1;
    __syncthreads();
    int* tmp = src; src = dst; dst = tmp;
  }
  int e0 = src[t] - c0;
  int e1 = src[t + 1024] - c1;
  off[t] = e0; off[t + 1024] = e1;
  pos_ctr[t] = e0; pos_ctr[t + 1024] = e1;
  dwf[t] = (float)c0; dwf[t + 1024] = (float)c1;  // exact int->f32
}

// ---------------- kernel: scatter row ids into buckets ----------------
__global__ __launch_bounds__(256) void k_scatter(const int* __restrict__ idx,
                                                 int* __restrict__ pos_ctr,
                                                 int* __restrict__ rowlist) {
  int n = blockIdx.x * 256 + threadIdx.x;
  int k = idx[n];
  int p = atomicAdd(&pos_ctr[k], 1);
  rowlist[p] = n;
}

// ---------------- kernel: per-code gather segment-sum (no atomics) ----------------
__global__ __launch_bounds__(128) void k_dwe(const float* __restrict__ x,
                                             const int* __restrict__ rowlist,
                                             const int* __restrict__ cnt,
                                             const int* __restrict__ off,
                                             float* __restrict__ dwe) {
  int k = blockIdx.x, d = threadIdx.x;
  int n = cnt[k], base = off[k];
  float s0 = 0.f, s1 = 0.f, s2 = 0.f, s3 = 0.f;
  int i = 0;
  for (; i + 4 <= n; i += 4) {
    int r0 = rowlist[base + i + 0];
    int r1 = rowlist[base + i + 1];
    int r2 = rowlist[base + i + 2];
    int r3 = rowlist[base + i + 3];
    s0 += x[(size_t)r0 * DDIM + d];
    s1 += x[(size_t)r1 * DDIM + d];
    s2 += x[(size_t)r2 * DDIM + d];
    s3 += x[(size_t)r3 * DDIM + d];
  }
  for (; i < n; ++i) {
    int r = rowlist[base + i];
    s0 += x[(size_t)r * DDIM + d];
  }
  dwe[(size_t)k * DDIM + d] = (s0 + s1) + (s2 + s3);
}

// ------- kernel: gather/quantize + ST output + loss partials (no atomics) -------
__global__ __launch_bounds__(256) void k_quant2(const float* __restrict__ x,
                                                const float* __restrict__ emb,
                                                const int* __restrict__ idx,
                                                float* __restrict__ out_q,
                                                double* __restrict__ partial_loss) {
#pragma clang fp contract(off)
  int t = blockIdx.x * 256 + threadIdx.x;
  int n = t >> 5, j = t & 31;
  int k = idx[n];
  float4 xv = ((const float4*)(x + (size_t)n * DDIM))[j];
  float4 ev = ((const float4*)(emb + (size_t)k * DDIM))[j];
  float d0 = ev.x - xv.x, d1 = ev.y - xv.y, d2 = ev.z - xv.z, d3 = ev.w - xv.w;
  float4 q;
  q.x = xv.x + d0; q.y = xv.y + d1; q.z = xv.z + d2; q.w = xv.w + d3;
  ((float4*)(out_q + (size_t)n * DDIM))[j] = q;

  float s = d0 * d0 + d1 * d1 + d2 * d2 + d3 * d3;
#pragma unroll
  for (int o = 32; o > 0; o >>= 1) s += __shfl_down(s, o);
  __shared__ float wsum[4];
  if ((threadIdx.x & 63) == 0) wsum[threadIdx.x >> 6] = s;
  __syncthreads();
  if (threadIdx.x == 0)
    partial_loss[blockIdx.x] =
        (double)((wsum[0] + wsum[1]) + (wsum[2] + wsum[3]));
}

// ---------------- kernel: cluster-size EMA, n-sum, smoothing, loss ----------------
__global__ __launch_bounds__(1024) void k_final1(const float* __restrict__ cs,
                                                 const float* __restrict__ dwf,
                                                 float* __restrict__ out_ncs,
                                                 float* __restrict__ smoothed,
                                                 const double* __restrict__ partial_loss,
                                                 float* __restrict__ out_loss) {
#pragma clang fp contract(off)
  __shared__ float red[1024];
  __shared__ double dred[1024];
  int t = threadIdx.x;
  float p0 = cs[t] * DECAYF;
  float p1 = cs[t + 1024] * DECAYF;
  float w0 = OMDF * dwf[t];
  float w1 = OMDF * dwf[t + 1024];
  float ncs0 = p0 + w0;
  float ncs1 = p1 + w1;
  out_ncs[t] = ncs0;
  out_ncs[t + 1024] = ncs1;
  red[t] = ncs0 + ncs1;
  double ds = 0.0;
#pragma unroll
  for (int i = 0; i < 8; ++i) ds += partial_loss[t + i * 1024];
  dred[t] = ds;
  __syncthreads();
  for (int o = 512; o > 0; o >>= 1) {
    if (t < o) { red[t] += red[t + o]; dred[t] += dred[t + o]; }
    __syncthreads();
  }
  float nsum = red[0];
  smoothed[t] = (ncs0 + EPSF) / (nsum + KEPSF) * nsum;
  smoothed[t + 1024] = (ncs1 + EPSF) / (nsum + KEPSF) * nsum;
  if (t == 0) {
    float m = (float)(dred[0] / (double)((size_t)NROWS * DDIM));
    out_loss[0] = m + 1.0f * m;
  }
}

// ---------------- kernel: embed_avg EMA + new embedding ----------------
__global__ __launch_bounds__(256) void k_final2(const float* __restrict__ ea,
                                                const float* __restrict__ dwe,
                                                const float* __restrict__ smoothed,
                                                float* __restrict__ out_ne,
                                                float* __restrict__ out_nea) {
#pragma clang fp contract(off)
  int i = blockIdx.x * 256 + threadIdx.x;
  float p = ea[i] * DECAYF;
  float w = OMDF * dwe[i];
  float nea = p + w;
  out_nea[i] = nea;
  out_ne[i] = nea / smoothed[i >> 7];
}

extern "C" void kernel_launch(void* const* d_in, const int* in_sizes, int n_in,
                              void* d_out, int out_size, void* d_ws, size_t ws_size,
                              hipStream_t stream) {
  const float* x   = (const float*)d_in[0];
  const float* emb = (const float*)d_in[1];
  const float* cs  = (const float*)d_in[2];
  const float* ea  = (const float*)d_in[3];

  float* out = (float*)d_out;
  float* out_q    = out;            // [N*D]
  float* out_loss = out + 8388608;  // [1]
  float* out_idx  = out + 8388609;  // [N] (float-encoded ints)
  float* out_ne   = out + 8454145;  // [K*D]
  float* out_ncs  = out + 8716289;  // [K]
  float* out_nea  = out + 8718337;  // [K*D]

  char* ws = (char*)d_ws;
  unsigned short* ehi = (unsigned short*)(ws + 0);         // 512 KB
  unsigned short* elo = (unsigned short*)(ws + 524288);    // 512 KB
  int*    idx      = (int*)(ws + 1048576);                 // 256 KB
  int*    flaglist = (int*)(ws + 1310720);                 // 256 KB
  int*    rowlist  = (int*)(ws + 1572864);                 // 256 KB
  int*    cnt      = (int*)(ws + 1835008);                 // 8 KB
  int*    flagcnt  = (int*)(ws + 1843200);                 // 64 B (padded)
  int*    pos_ctr  = (int*)(ws + 1843264);                 // 8 KB
  int*    off      = (int*)(ws + 1851456);                 // 8 KB
  float*  dwf      = (float*)(ws + 1859648);               // 8 KB
  float*  se       = (float*)(ws + 1867840);               // 8 KB
  float*  smoothed = (float*)(ws + 1876032);               // 8 KB
  float*  dwe      = (float*)(ws + 1884224);               // 1 MB
  double* partial_loss = (double*)(ws + 2932800);          // 64 KB (8192 doubles)

  // zero only histogram + flag counter (everything else fully overwritten)
  hipMemsetAsync(ws + 1835008, 0, 8192 + 64, stream);

  k_split<<<(KCODE * DDIM) / 256, 256, 0, stream>>>(emb, ehi, elo);
  k_sumsq_emb<<<(KCODE + 255) / 256, 256, 0, stream>>>(emb, se);
  k_screen<<<NROWS / 128, 256, 0, stream>>>(x, ehi, elo, se, out_idx, idx, flaglist, flagcnt);
  k_exact<<<128, 256, 0, stream>>>(x, emb, se, flaglist, flagcnt, idx, out_idx);
  k_hist<<<NROWS / 256, 256, 0, stream>>>(idx, cnt);
  k_scan<<<1, 1024, 0, stream>>>(cnt, off, pos_ctr, dwf);
  k_scatter<<<NROWS / 256, 256, 0, stream>>>(idx, pos_ctr, rowlist);
  k_dwe<<<KCODE, 128, 0, stream>>>(x, rowlist, cnt, off, dwe);
  k_quant2<<<(NROWS * 32) / 256, 256, 0, stream>>>(x, emb, idx, out_q, partial_loss);
  k_final1<<<1, 1024, 0, stream>>>(cs, dwf, out_ncs, smoothed, partial_loss, out_loss);
  k_final2<<<(KCODE * DDIM) / 256, 256, 0, stream>>>(ea, dwe, smoothed, out_ne, out_nea);
}